// Round 1
// baseline (291.963 us; speedup 1.0000x reference)
//
#include <hip/hip_runtime.h>

// XOR-conv as implicit-GEMM MFMA (bf16 inputs, fp32 accum).
// out[b,co,ho,wo] = sum_{ci,kh,kw} x[b,ci,ho+kh,wo+kw] * (1-2*W[co,ci,kh,kw])
// Shapes: B=32, CI=128, H=W=64, CO=256, K=3, HO=WO=62.

typedef __bf16 bf16x8 __attribute__((ext_vector_type(8)));
typedef float  f32x4  __attribute__((ext_vector_type(4)));

#define CIPAD 40  // 32-ci chunk padded to 40 ushorts (80B -> 20-bank stride, 2-way max = free)

// ---- prepack: W fp32 [co][ci][3][3] in {0,1}  ->  effw bf16 bits [e][co][ci], e=kh*3+kw ----
__global__ void prepack_w_kernel(const float* __restrict__ Wf,
                                 unsigned short* __restrict__ effw) {
  int idx = blockIdx.x * 256 + threadIdx.x;     // 9*256*128 = 294912
  if (idx >= 9 * 256 * 128) return;
  int ci = idx & 127;
  int t  = idx >> 7;
  int co = t & 255;
  int e  = t >> 8;
  float w = Wf[(co * 128 + ci) * 9 + e];
  __bf16 h = (__bf16)(1.0f - 2.0f * w);         // exactly +-1
  unsigned short u; __builtin_memcpy(&u, &h, 2);
  effw[idx] = u;
}

// Block: 256 threads = 4 waves. Tile: 128 co x (4 output rows x 64 virtual cols).
// Wave w owns output row w (ho = hbase+w), all 8 co 16-tiles, 4 col 16-tiles.
__global__ __launch_bounds__(256, 2)
void xorconv_mfma_kernel(const float* __restrict__ x,
                         const unsigned short* __restrict__ effw,
                         float* __restrict__ out) {
  __shared__ __align__(16) unsigned short xs[6 * 66 * CIPAD];  // [r=6][c=66][ci32 pad40] 31.7KB
  __shared__ __align__(16) unsigned short wsm[128 * CIPAD];    // [co=128][ci32 pad40]    10.2KB

  const int tid    = threadIdx.x;
  const int co_blk = blockIdx.x * 128;   // 0 or 128
  const int hbase  = blockIdx.y * 4;     // 0..60
  const int bb     = blockIdx.z;         // batch

  const int wv   = tid >> 6;
  const int lane = tid & 63;
  const int quad = lane >> 4;
  const int l16  = lane & 15;

  f32x4 acc[8][4];
  #pragma unroll
  for (int i = 0; i < 8; ++i)
    #pragma unroll
    for (int j = 0; j < 4; ++j)
      acc[i][j] = (f32x4){0.f, 0.f, 0.f, 0.f};

  unsigned int* xs32 = (unsigned int*)xs;

  for (int cc = 0; cc < 4; ++cc) {
    const int c0 = cc * 32;

    // ---- stage x tile: ci in [c0,c0+32), input rows hbase..hbase+5, cols 0..65 ----
    // thread handles a 2x2 (ci-pair x col-pair) cell; fp32 load -> bf16 -> LDS
    for (int p2 = tid; p2 < 6 * 33 * 16; p2 += 256) {
      int c2  = p2 % 33;
      int t2  = p2 / 33;
      int ci2 = t2 & 15;
      int r   = t2 >> 4;
      int c   = c2 * 2;
      int h_in = hbase + r; if (h_in > 63) h_in = 63;   // clamp: only feeds masked outputs
      int c_in = c;         if (c_in > 62) c_in = 62;   // clamp cols 64/65 (masked outputs)
      const float* gp = x + (((size_t)(bb * 128 + c0 + ci2 * 2) * 64 + h_in) * 64 + c_in);
      float f00 = gp[0],    f01 = gp[1];        // (ci,   c), (ci,   c+1)
      float f10 = gp[4096], f11 = gp[4097];     // (ci+1, c), (ci+1, c+1)
      __bf16 h00 = (__bf16)f00, h01 = (__bf16)f01, h10 = (__bf16)f10, h11 = (__bf16)f11;
      unsigned short u00, u01, u10, u11;
      __builtin_memcpy(&u00, &h00, 2); __builtin_memcpy(&u01, &h01, 2);
      __builtin_memcpy(&u10, &h10, 2); __builtin_memcpy(&u11, &h11, 2);
      xs32[(r * 66 + c) * (CIPAD / 2) + ci2]       = (unsigned)u00 | ((unsigned)u10 << 16);
      xs32[(r * 66 + c + 1) * (CIPAD / 2) + ci2]   = (unsigned)u01 | ((unsigned)u11 << 16);
    }

    // ---- 9 filter taps; each tap is one k=32 MFMA step over this ci chunk ----
    for (int e = 0; e < 9; ++e) {
      const int kh = e / 3;
      const int kw = e - 3 * kh;

      // stage W tile [128co][32ci] from prepacked bf16 (16B copies)
      for (int s = tid; s < 512; s += 256) {
        int co = s >> 2, q = s & 3;
        const uint4 v = *(const uint4*)(effw + ((size_t)(e * 256 + co_blk + co) * 128 + c0 + q * 8));
        *(uint4*)&wsm[co * CIPAD + q * 8] = v;
      }
      __syncthreads();   // covers xs (on e==0) and wsm writes

      const int rr = wv + kh;
      bf16x8 bfr[4];
      #pragma unroll
      for (int j = 0; j < 4; ++j) {
        int ccol = j * 16 + l16 + kw;                       // input col for this n-lane
        bfr[j] = *(const bf16x8*)&xs[(rr * 66 + ccol) * CIPAD + quad * 8];
      }
      #pragma unroll
      for (int mt = 0; mt < 8; ++mt) {
        bf16x8 af = *(const bf16x8*)&wsm[(mt * 16 + l16) * CIPAD + quad * 8];
        #pragma unroll
        for (int j = 0; j < 4; ++j)
          acc[mt][j] = __builtin_amdgcn_mfma_f32_16x16x32_bf16(af, bfr[j], acc[mt][j], 0, 0, 0);
      }
      __syncthreads();   // compute done before next stage overwrites LDS
    }
  }

  // ---- epilogue: C/D layout col(n)=lane&15, row(m)=quad*4+reg ----
  const int ho = hbase + wv;
  if (ho < 62) {
    #pragma unroll
    for (int mt = 0; mt < 8; ++mt) {
      const int co = co_blk + mt * 16 + quad * 4;
      #pragma unroll
      for (int j = 0; j < 4; ++j) {
        const int wo = j * 16 + l16;
        if (wo < 62) {
          float* op = out + (((size_t)(bb * 256 + co) * 62 + ho) * 62 + wo);
          #pragma unroll
          for (int rg = 0; rg < 4; ++rg)
            op[(size_t)rg * 3844] = acc[mt][j][rg];
        }
      }
    }
  }
}

extern "C" void kernel_launch(void* const* d_in, const int* in_sizes, int n_in,
                              void* d_out, int out_size, void* d_ws, size_t ws_size,
                              hipStream_t stream) {
  const float* x  = (const float*)d_in[0];
  const float* Wf = (const float*)d_in[1];
  float* out = (float*)d_out;
  unsigned short* effw = (unsigned short*)d_ws;   // 9*256*128*2 = 1.13 MB scratch

  prepack_w_kernel<<<dim3((9 * 256 * 128 + 255) / 256), dim3(256), 0, stream>>>(Wf, effw);

  dim3 grid(2, 16, 32);   // co-tiles x ho-tiles(4 rows, last masked) x batch
  xorconv_mfma_kernel<<<grid, dim3(256), 0, stream>>>(x, effw, out);
}

// Round 2
// 284.007 us; speedup vs baseline: 1.0280x; 1.0280x over previous
//
#include <hip/hip_runtime.h>

// XOR-conv as implicit-GEMM MFMA (bf16 inputs, fp32 accum).
// out[b,co,ho,wo] = sum_{ci,kh,kw} x[b,ci,ho+kh,wo+kw] * (1-2*W[co,ci,kh,kw])
// Shapes: B=32, CI=128, H=W=64, CO=256, K=3, HO=WO=62.
//
// R2: W prepacked into exact MFMA A-fragment order and loaded straight from
// global (L2-resident, 1.13MB) -> no W LDS staging, 8 barriers/block not 72.

typedef __bf16 bf16x8 __attribute__((ext_vector_type(8)));
typedef float  f32x4  __attribute__((ext_vector_type(4)));

#define CIPAD 40  // 32-ci chunk padded to 40 ushorts (80B col stride; frag reads 2-way = free)

// ---- prepack: W fp32 [co][ci][3][3] in {0,1} -> bf16 bits in A-frag order ----
// layout: [e(9)][cc(4)][tile(16)][lane(64)][j(8)]  (ushort)
//   co = tile*16 + (lane&15), ci = cc*32 + (lane>>4)*8 + j, e = kh*3+kw
__global__ void prepack_w_kernel(const float* __restrict__ Wf,
                                 unsigned short* __restrict__ effw) {
  int idx = blockIdx.x * 256 + threadIdx.x;     // 9*4*16*64*8 = 294912
  if (idx >= 9 * 4 * 16 * 64 * 8) return;
  int j    = idx & 7;
  int lane = (idx >> 3) & 63;
  int tile = (idx >> 9) & 15;
  int cc   = (idx >> 13) & 3;
  int e    = idx >> 15;
  int co = tile * 16 + (lane & 15);
  int ci = cc * 32 + (lane >> 4) * 8 + j;
  float w = Wf[(co * 128 + ci) * 9 + e];
  __bf16 h = (__bf16)(1.0f - 2.0f * w);         // exactly +-1
  unsigned short u; __builtin_memcpy(&u, &h, 2);
  effw[idx] = u;
}

// Block: 256 threads = 4 waves. Tile: 128 co x (4 output rows x 64 virtual cols).
// Wave w owns output row w (ho = hbase+w), all 8 co 16-tiles, 4 col 16-tiles.
__global__ __launch_bounds__(256, 2)
void xorconv_mfma_kernel(const float* __restrict__ x,
                         const unsigned short* __restrict__ effw,
                         float* __restrict__ out) {
  __shared__ __align__(16) unsigned short xs[6 * 66 * CIPAD];  // 31.7KB

  const int tid    = threadIdx.x;
  const int bxc    = blockIdx.x;         // co-half: 0 or 1
  const int co_blk = bxc * 128;
  const int hbase  = blockIdx.y * 4;     // 0..60
  const int bb     = blockIdx.z;         // batch

  const int wv   = tid >> 6;
  const int lane = tid & 63;
  const int quad = lane >> 4;
  const int l16  = lane & 15;

  f32x4 acc[8][4];
  #pragma unroll
  for (int i = 0; i < 8; ++i)
    #pragma unroll
    for (int j = 0; j < 4; ++j)
      acc[i][j] = (f32x4){0.f, 0.f, 0.f, 0.f};

  unsigned int* xs32 = (unsigned int*)xs;

  for (int cc = 0; cc < 4; ++cc) {
    const int c0 = cc * 32;

    // ---- stage x tile: ci in [c0,c0+32), rows hbase..hbase+5, cols 0..65 ----
    for (int p2 = tid; p2 < 6 * 33 * 16; p2 += 256) {
      int c2  = p2 % 33;
      int t2  = p2 / 33;
      int ci2 = t2 & 15;
      int r   = t2 >> 4;
      int c   = c2 * 2;
      int h_in = hbase + r; if (h_in > 63) h_in = 63;   // clamp: feeds only masked outputs
      int c_in = c;         if (c_in > 62) c_in = 62;
      const float* gp = x + (((size_t)(bb * 128 + c0 + ci2 * 2) * 64 + h_in) * 64 + c_in);
      float f00 = gp[0],    f01 = gp[1];
      float f10 = gp[4096], f11 = gp[4097];
      __bf16 h00 = (__bf16)f00, h01 = (__bf16)f01, h10 = (__bf16)f10, h11 = (__bf16)f11;
      unsigned short u00, u01, u10, u11;
      __builtin_memcpy(&u00, &h00, 2); __builtin_memcpy(&u01, &h01, 2);
      __builtin_memcpy(&u10, &h10, 2); __builtin_memcpy(&u11, &h11, 2);
      xs32[(r * 66 + c) * (CIPAD / 2) + ci2]     = (unsigned)u00 | ((unsigned)u10 << 16);
      xs32[(r * 66 + c + 1) * (CIPAD / 2) + ci2] = (unsigned)u01 | ((unsigned)u11 << 16);
    }
    __syncthreads();   // xs ready

    // ---- 9 filter taps, barrier-free: W frags straight from global (L2-hot) ----
    for (int e = 0; e < 9; ++e) {
      const int kh = e / 3;
      const int kw = e - 3 * kh;
      const int rr = wv + kh;

      bf16x8 bfr[4];
      #pragma unroll
      for (int j = 0; j < 4; ++j) {
        int ccol = j * 16 + l16 + kw;
        bfr[j] = *(const bf16x8*)&xs[(rr * 66 + ccol) * CIPAD + quad * 8];
      }
      const unsigned short* wp =
          effw + ((((size_t)e * 4 + cc) * 16 + bxc * 8) * 64 + lane) * 8;
      #pragma unroll
      for (int mt = 0; mt < 8; ++mt) {
        bf16x8 af = *(const bf16x8*)(wp + (size_t)mt * 512);
        #pragma unroll
        for (int j = 0; j < 4; ++j)
          acc[mt][j] = __builtin_amdgcn_mfma_f32_16x16x32_bf16(af, bfr[j], acc[mt][j], 0, 0, 0);
      }
    }
    __syncthreads();   // taps done before next chunk overwrites xs
  }

  // ---- epilogue: C/D layout col(n)=lane&15, row(m)=quad*4+reg ----
  const int ho = hbase + wv;
  if (ho < 62) {
    #pragma unroll
    for (int mt = 0; mt < 8; ++mt) {
      const int co = co_blk + mt * 16 + quad * 4;
      #pragma unroll
      for (int j = 0; j < 4; ++j) {
        const int wo = j * 16 + l16;
        if (wo < 62) {
          float* op = out + (((size_t)(bb * 256 + co) * 62 + ho) * 62 + wo);
          #pragma unroll
          for (int rg = 0; rg < 4; ++rg)
            op[(size_t)rg * 3844] = acc[mt][j][rg];
        }
      }
    }
  }
}

extern "C" void kernel_launch(void* const* d_in, const int* in_sizes, int n_in,
                              void* d_out, int out_size, void* d_ws, size_t ws_size,
                              hipStream_t stream) {
  const float* x  = (const float*)d_in[0];
  const float* Wf = (const float*)d_in[1];
  float* out = (float*)d_out;
  unsigned short* effw = (unsigned short*)d_ws;   // 9*4*16*64*8*2 = 1.13 MB scratch

  prepack_w_kernel<<<dim3((9 * 4 * 16 * 64 * 8 + 255) / 256), dim3(256), 0, stream>>>(Wf, effw);

  dim3 grid(2, 16, 32);   // co-halves x ho-tiles(4 rows) x batch
  xorconv_mfma_kernel<<<grid, dim3(256), 0, stream>>>(x, effw, out);
}